// Round 1
// baseline (399.140 us; speedup 1.0000x reference)
//
#include <hip/hip_runtime.h>
#include <cmath>

#define B_    2
#define NQ_   11531
#define NV_   11531
#define DM_   256
#define H_    8
#define L_    4
#define P_    4

// ---------------------------------------------------------------------------
// Tiled fp32 GEMM:  C[M x TN] = A[M x 256] * W[256 x TN] + bias[TN]
// 64x64 block tile, 4x4 per-thread microtile, K-step 32.
// ---------------------------------------------------------------------------
template <int TN>
__global__ __launch_bounds__(256) void gemm_f32(const float* __restrict__ A,
                                                const float* __restrict__ W,
                                                const float* __restrict__ bias,
                                                float* __restrict__ C, int M) {
    constexpr int K = 256;
    __shared__ float As[32][68];  // [k][m], +4 pad: 16B-aligned rows, no write conflicts
    __shared__ float Bs[32][64];  // [k][n]

    const int tid = threadIdx.x;
    const int bm = blockIdx.y * 64;
    const int bn = blockIdx.x * 64;
    const int tr = tid >> 4;   // 0..15
    const int tc = tid & 15;   // 0..15

    float acc[4][4] = {};

    for (int k0 = 0; k0 < K; k0 += 32) {
#pragma unroll
        for (int j = 0; j < 2; ++j) {
            const int flat = tid + j * 256;        // 0..511
            // A tile: 64 rows x 32 k (512 float4)
            const int arow = flat >> 3;            // 0..63
            const int akk = (flat & 7) << 2;       // 0,4,..,28
            float4 av = make_float4(0.f, 0.f, 0.f, 0.f);
            const int gr = bm + arow;
            if (gr < M) av = *(const float4*)&A[(size_t)gr * K + k0 + akk];
            As[akk + 0][arow] = av.x;
            As[akk + 1][arow] = av.y;
            As[akk + 2][arow] = av.z;
            As[akk + 3][arow] = av.w;
            // B tile: 32 k x 64 n (512 float4)
            const int krow = flat >> 4;            // 0..31
            const int nn = (flat & 15) << 2;       // 0..60
            float4 wv = *(const float4*)&W[(size_t)(k0 + krow) * TN + bn + nn];
            *(float4*)&Bs[krow][nn] = wv;
        }
        __syncthreads();
#pragma unroll
        for (int kk = 0; kk < 32; ++kk) {
            const float4 a = *(const float4*)&As[kk][tr * 4];
            const float4 b = *(const float4*)&Bs[kk][tc * 4];
            acc[0][0] = fmaf(a.x, b.x, acc[0][0]);
            acc[0][1] = fmaf(a.x, b.y, acc[0][1]);
            acc[0][2] = fmaf(a.x, b.z, acc[0][2]);
            acc[0][3] = fmaf(a.x, b.w, acc[0][3]);
            acc[1][0] = fmaf(a.y, b.x, acc[1][0]);
            acc[1][1] = fmaf(a.y, b.y, acc[1][1]);
            acc[1][2] = fmaf(a.y, b.z, acc[1][2]);
            acc[1][3] = fmaf(a.y, b.w, acc[1][3]);
            acc[2][0] = fmaf(a.z, b.x, acc[2][0]);
            acc[2][1] = fmaf(a.z, b.y, acc[2][1]);
            acc[2][2] = fmaf(a.z, b.z, acc[2][2]);
            acc[2][3] = fmaf(a.z, b.w, acc[2][3]);
            acc[3][0] = fmaf(a.w, b.x, acc[3][0]);
            acc[3][1] = fmaf(a.w, b.y, acc[3][1]);
            acc[3][2] = fmaf(a.w, b.z, acc[3][2]);
            acc[3][3] = fmaf(a.w, b.w, acc[3][3]);
        }
        __syncthreads();
    }

    const float4 bv = *(const float4*)&bias[bn + tc * 4];
#pragma unroll
    for (int m = 0; m < 4; ++m) {
        const int gr = bm + tr * 4 + m;
        if (gr < M) {
            float4 o;
            o.x = acc[m][0] + bv.x;
            o.y = acc[m][1] + bv.y;
            o.z = acc[m][2] + bv.z;
            o.w = acc[m][3] + bv.w;
            *(float4*)&C[(size_t)gr * TN + bn + tc * 4] = o;
        }
    }
}

// ---------------------------------------------------------------------------
// Per-(b,q) sampling: softmax over 16 logits per head, then H*L*P bilinear
// gathers from projected value, accumulate 256-dim sampled vector.
// One block of 256 threads per (b,q); channel c = tid = h*32+d.
// ---------------------------------------------------------------------------
__global__ __launch_bounds__(256) void msda_sample_kernel(
    const float* __restrict__ v,      // (B*NV, 256) projected value
    const float* __restrict__ offr,   // (B*NQ, 256)
    const float* __restrict__ attnr,  // (B*NQ, 128) logits
    const float* __restrict__ refp,   // (B, NQ, 4, 2)
    float* __restrict__ samp) {       // (B*NQ, 256)
    const int bq = blockIdx.x;
    const int b = bq / NQ_;
    const int tid = threadIdx.x;

    __shared__ float s_off[256];
    __shared__ float s_attn[128];

    s_off[tid] = offr[(size_t)bq * 256 + tid];

    {
        const float* at = attnr + (size_t)bq * 128;
        float x = (tid < 128) ? at[tid] : -1e30f;
        float m = x;
#pragma unroll
        for (int s = 8; s >= 1; s >>= 1) m = fmaxf(m, __shfl_xor(m, s, 16));
        const float e = __expf(x - m);
        float ssum = e;
#pragma unroll
        for (int s = 8; s >= 1; s >>= 1) ssum += __shfl_xor(ssum, s, 16);
        if (tid < 128) s_attn[tid] = e / ssum;
    }
    __syncthreads();

    const int h = tid >> 5;
    const int lhs[4] = {76, 38, 19, 10};
    const int lws[4] = {114, 57, 29, 15};
    const int sts[4] = {0, 8664, 10830, 11381};

    const float* vb = v + (size_t)b * NV_ * 256;
    const float* rp = refp + (size_t)bq * 8;

    float out_acc = 0.f;
#pragma unroll
    for (int l = 0; l < 4; ++l) {
        const float rx = rp[l * 2 + 0];
        const float ry = rp[l * 2 + 1];
        const int lw = lws[l], lh = lhs[l];
        const float flw = (float)lw, flh = (float)lh;
        const int base = sts[l];
#pragma unroll
        for (int p = 0; p < 4; ++p) {
            const int oidx = ((h * 4 + l) * 4 + p) * 2;
            const float px = rx * flw + s_off[oidx + 0] - 0.5f;
            const float py = ry * flh + s_off[oidx + 1] - 0.5f;
            const float wa = s_attn[h * 16 + l * 4 + p];
            const float x0f = floorf(px);
            const float y0f = floorf(py);
            const int x0 = (int)x0f;
            const int y0 = (int)y0f;
            const float fx = px - x0f;
            const float fy = py - y0f;
            const bool vx0 = (x0 >= 0) && (x0 <= lw - 1);
            const bool vx1 = (x0 >= -1) && (x0 <= lw - 2);
            const bool vy0 = (y0 >= 0) && (y0 <= lh - 1);
            const bool vy1 = (y0 >= -1) && (y0 <= lh - 2);
            float sp = 0.f;
            if (vy0) {
                const int rb = base + y0 * lw;
                if (vx0) sp = fmaf((1.f - fx) * (1.f - fy), vb[(size_t)(rb + x0) * 256 + tid], sp);
                if (vx1) sp = fmaf(fx * (1.f - fy), vb[(size_t)(rb + x0 + 1) * 256 + tid], sp);
            }
            if (vy1) {
                const int rb = base + (y0 + 1) * lw;
                if (vx0) sp = fmaf((1.f - fx) * fy, vb[(size_t)(rb + x0) * 256 + tid], sp);
                if (vx1) sp = fmaf(fx * fy, vb[(size_t)(rb + x0 + 1) * 256 + tid], sp);
            }
            out_acc = fmaf(wa, sp, out_acc);
        }
    }
    samp[(size_t)bq * 256 + tid] = out_acc;
}

// ---------------------------------------------------------------------------
extern "C" void kernel_launch(void* const* d_in, const int* in_sizes, int n_in,
                              void* d_out, int out_size, void* d_ws, size_t ws_size,
                              hipStream_t stream) {
    const float* query  = (const float*)d_in[0];
    const float* refp   = (const float*)d_in[1];
    const float* value  = (const float*)d_in[2];
    const float* W_off  = (const float*)d_in[3];
    const float* b_off  = (const float*)d_in[4];
    const float* W_attn = (const float*)d_in[5];
    const float* b_attn = (const float*)d_in[6];
    const float* W_val  = (const float*)d_in[7];
    const float* b_val  = (const float*)d_in[8];
    const float* W_out  = (const float*)d_in[9];
    const float* b_out  = (const float*)d_in[10];
    float* out = (float*)d_out;

    const int M = B_ * NQ_;  // 23062 rows for every GEMM

    float* ws = (float*)d_ws;
    float* ws_v    = ws;                           // M*256
    float* ws_off  = ws_v + (size_t)M * 256;       // M*256
    float* ws_attn = ws_off + (size_t)M * 256;     // M*128
    float* ws_samp = ws_attn + (size_t)M * 128;    // M*256

    dim3 blk(256);
    dim3 g256(4, (M + 63) / 64);
    dim3 g128(2, (M + 63) / 64);

    gemm_f32<256><<<g256, blk, 0, stream>>>(value, W_val, b_val, ws_v, M);
    gemm_f32<256><<<g256, blk, 0, stream>>>(query, W_off, b_off, ws_off, M);
    gemm_f32<128><<<g128, blk, 0, stream>>>(query, W_attn, b_attn, ws_attn, M);
    msda_sample_kernel<<<dim3(M), blk, 0, stream>>>(ws_v, ws_off, ws_attn, refp, ws_samp);
    gemm_f32<256><<<g256, blk, 0, stream>>>(ws_samp, W_out, b_out, out, M);
}

// Round 2
// 174.418 us; speedup vs baseline: 2.2884x; 2.2884x over previous
//
#include <hip/hip_runtime.h>
#include <cmath>

#define B_    2
#define NQ_   11531
#define NV_   11531
#define M_    (B_ * NQ_)   // 23062

typedef unsigned short u16;
typedef __attribute__((ext_vector_type(8))) short bf16x8;
typedef __attribute__((ext_vector_type(4))) float f32x4;

__device__ __forceinline__ u16 f2bf(float f) {
    union { float f; unsigned u; } v; v.f = f;
    unsigned r = v.u + 0x7FFFu + ((v.u >> 16) & 1u);  // RNE
    return (u16)(r >> 16);
}

// ---------------------------------------------------------------------------
// Transpose + cast up to 3 weight matrices: W[K=256][N] fp32 -> WT[N][256] bf16
// grid (8, 8, nz), block 256. z=2 slot is the N=128 matrix.
// ---------------------------------------------------------------------------
__global__ __launch_bounds__(256) void transpose_cast3(
    const float* __restrict__ W0, const float* __restrict__ W1, const float* __restrict__ W2,
    u16* __restrict__ T0, u16* __restrict__ T1, u16* __restrict__ T2) {
    constexpr int K = 256;
    const int z = blockIdx.z;
    const float* W = (z == 0) ? W0 : (z == 1) ? W1 : W2;
    u16* T = (z == 0) ? T0 : (z == 1) ? T1 : T2;
    const int N = (z == 2) ? 128 : 256;
    const int n0 = blockIdx.x * 32, k0 = blockIdx.y * 32;
    if (n0 >= N) return;
    __shared__ float t[32][33];
    const int c = threadIdx.x & 31, r0 = threadIdx.x >> 5;
#pragma unroll
    for (int i = 0; i < 4; ++i)
        t[r0 + i * 8][c] = W[(size_t)(k0 + r0 + i * 8) * N + n0 + c];
    __syncthreads();
#pragma unroll
    for (int i = 0; i < 4; ++i)
        T[(size_t)(n0 + r0 + i * 8) * K + k0 + c] = f2bf(t[c][r0 + i * 8]);
}

// ---------------------------------------------------------------------------
// bf16 MFMA GEMM: C[M x TN] = A[M x 256] (fp32, cast in staging) * WT^T + bias
// WT is [TN][256] bf16 (pre-transposed). 128x128 tile, 4 waves (2x2), each
// wave 64x64 = 4x4 fragments of 16x16x32 MFMA. LDS stride 40 shorts (80 B):
// 16B-aligned rows, 2-way-max bank aliasing on b128 frag reads (free).
// ---------------------------------------------------------------------------
template <int TN>
__global__ __launch_bounds__(256) void gemm_bf16(const float* __restrict__ A,
                                                 const u16* __restrict__ WT,
                                                 const float* __restrict__ bias,
                                                 float* __restrict__ C, int M) {
    constexpr int K = 256;
    __shared__ __align__(16) short A_l[128 * 40];
    __shared__ __align__(16) short B_l[128 * 40];
    const int tid = threadIdx.x;
    const int bm = blockIdx.y * 128;
    const int bn = blockIdx.x * 128;
    const int w = tid >> 6;
    const int lane = tid & 63;
    const int wr = (w >> 1) * 64;
    const int wc = (w & 1) * 64;
    const int lr = lane & 15;
    const int kg = (lane >> 4) * 8;

    f32x4 acc[4][4] = {};

    for (int k0 = 0; k0 < K; k0 += 32) {
        // stage A tile (128 rows x 32 k), fp32 -> bf16
#pragma unroll
        for (int i = 0; i < 4; ++i) {
            const int vid = tid + i * 256;       // float4 id 0..1023
            const int ar = vid >> 3;             // 0..127
            const int ak = (vid & 7) * 4;        // 0..28
            const int gr = bm + ar;
            float4 av = make_float4(0.f, 0.f, 0.f, 0.f);
            if (gr < M) av = *(const float4*)&A[(size_t)gr * K + k0 + ak];
            ushort4 hv;
            hv.x = f2bf(av.x); hv.y = f2bf(av.y); hv.z = f2bf(av.z); hv.w = f2bf(av.w);
            *(ushort4*)&A_l[ar * 40 + ak] = hv;
        }
        // stage B tile (128 n x 32 k) from bf16 WT[n][k] — contiguous in k
#pragma unroll
        for (int i = 0; i < 2; ++i) {
            const int vid = tid + i * 256;       // 8-short chunk id 0..511
            const int nr = vid >> 2;             // 0..127
            const int kk = (vid & 3) * 8;        // 0,8,16,24
            const uint4 wv = *(const uint4*)&WT[(size_t)(bn + nr) * K + k0 + kk];
            *(uint4*)&B_l[nr * 40 + kk] = wv;
        }
        __syncthreads();
        bf16x8 af[4], bfr[4];
#pragma unroll
        for (int m = 0; m < 4; ++m)
            af[m] = *(const bf16x8*)&A_l[(wr + m * 16 + lr) * 40 + kg];
#pragma unroll
        for (int n = 0; n < 4; ++n)
            bfr[n] = *(const bf16x8*)&B_l[(wc + n * 16 + lr) * 40 + kg];
#pragma unroll
        for (int m = 0; m < 4; ++m)
#pragma unroll
            for (int n = 0; n < 4; ++n)
                acc[m][n] = __builtin_amdgcn_mfma_f32_16x16x32_bf16(af[m], bfr[n], acc[m][n], 0, 0, 0);
        __syncthreads();
    }

#pragma unroll
    for (int n = 0; n < 4; ++n) {
        const int gcol = bn + wc + n * 16 + lr;
        const float bv = bias[gcol];
#pragma unroll
        for (int m = 0; m < 4; ++m) {
            const int rbase = bm + wr + m * 16 + (lane >> 4) * 4;
#pragma unroll
            for (int j = 0; j < 4; ++j) {
                const int grow = rbase + j;
                if (grow < M) C[(size_t)grow * TN + gcol] = acc[m][n][j] + bv;
            }
        }
    }
}

// ---------------------------------------------------------------------------
// Sampler v2: block = 256 threads handles 4 queries.
// Phase 1: 512 sample-points computed once each (softmax via 16-lane shfl,
//          bilinear*attn weights + clamped value-row indices) -> LDS.
// Phase 2: 64 lanes/query, 4 channels/lane (float4 gathers).
// ---------------------------------------------------------------------------
__global__ __launch_bounds__(256) void msda_sample_v2(
    const float* __restrict__ v,      // (B*NV, 256) projected value
    const float* __restrict__ offr,   // (B*NQ, 256)
    const float* __restrict__ attnr,  // (B*NQ, 128) logits
    const float* __restrict__ refp,   // (B, NQ, 4, 2)
    float* __restrict__ samp) {       // (B*NQ, 256)
    __shared__ __align__(16) float4 s_w4[512];  // [(qi*16+samp)*8 + h]
    __shared__ __align__(16) int4   s_i4[512];
    const int tid = threadIdx.x;
    const int bq0 = blockIdx.x * 4;

#pragma unroll
    for (int half = 0; half < 2; ++half) {
        const int s = tid + half * 256;
        const int qi = s >> 7;
        const int rem = s & 127;          // h*16 + l*4 + p
        const int h = rem >> 4;
        const int sampi = rem & 15;
        const int l = sampi >> 2;
        int bq = bq0 + qi;
        if (bq >= M_) bq = M_ - 1;        // clamp: garbage-free, result unused
        const int b = bq / NQ_;

        const float logit = attnr[(size_t)bq * 128 + rem];
        float mx = logit;
#pragma unroll
        for (int t = 8; t >= 1; t >>= 1) mx = fmaxf(mx, __shfl_xor(mx, t, 16));
        const float e = __expf(logit - mx);
        float sm = e;
#pragma unroll
        for (int t = 8; t >= 1; t >>= 1) sm += __shfl_xor(sm, t, 16);
        const float aw = e / sm;

        const float2 off = *(const float2*)&offr[(size_t)bq * 256 + rem * 2];
        const float2 rxy = *(const float2*)&refp[(size_t)bq * 8 + l * 2];
        const int lw = (l == 0) ? 114 : (l == 1) ? 57 : (l == 2) ? 29 : 15;
        const int lh = (l == 0) ? 76 : (l == 1) ? 38 : (l == 2) ? 19 : 10;
        const int st = (l == 0) ? 0 : (l == 1) ? 8664 : (l == 2) ? 10830 : 11381;
        const int base = b * NV_ + st;

        const float px = rxy.x * (float)lw + off.x - 0.5f;
        const float py = rxy.y * (float)lh + off.y - 0.5f;
        const float x0f = floorf(px), y0f = floorf(py);
        const int x0 = (int)x0f, y0 = (int)y0f;
        const float fx = px - x0f, fy = py - y0f;
        const bool vx0 = (x0 >= 0) && (x0 < lw);
        const bool vx1 = (x0 >= -1) && (x0 < lw - 1);
        const bool vy0 = (y0 >= 0) && (y0 < lh);
        const bool vy1 = (y0 >= -1) && (y0 < lh - 1);
        const int r0 = base + y0 * lw + x0;
        const int r1 = r0 + lw;
        float4 wv; int4 iv;
        wv.x = (vy0 && vx0) ? aw * (1.f - fx) * (1.f - fy) : 0.f; iv.x = (vy0 && vx0) ? r0 : 0;
        wv.y = (vy0 && vx1) ? aw * fx * (1.f - fy) : 0.f;         iv.y = (vy0 && vx1) ? r0 + 1 : 0;
        wv.z = (vy1 && vx0) ? aw * (1.f - fx) * fy : 0.f;         iv.z = (vy1 && vx0) ? r1 : 0;
        wv.w = (vy1 && vx1) ? aw * fx * fy : 0.f;                 iv.w = (vy1 && vx1) ? r1 + 1 : 0;
        const int slot = (qi * 16 + sampi) * 8 + h;
        s_w4[slot] = wv;
        s_i4[slot] = iv;
    }
    __syncthreads();

    const int qi = tid >> 6;
    const int lane = tid & 63;
    const int h = lane >> 3;
    const int c = lane * 4;               // channel = h*32 + (lane&7)*4
    const int bq = bq0 + qi;
    float4 acc = make_float4(0.f, 0.f, 0.f, 0.f);
#pragma unroll
    for (int sp = 0; sp < 16; ++sp) {
        const int slot = (qi * 16 + sp) * 8 + h;   // 8 heads -> 128 B contiguous, conflict-free
        const float4 w = s_w4[slot];
        const int4 i4 = s_i4[slot];
        const float4 v0 = *(const float4*)&v[((size_t)i4.x << 8) + c];
        const float4 v1 = *(const float4*)&v[((size_t)i4.y << 8) + c];
        const float4 v2 = *(const float4*)&v[((size_t)i4.z << 8) + c];
        const float4 v3 = *(const float4*)&v[((size_t)i4.w << 8) + c];
        acc.x = fmaf(w.x, v0.x, acc.x); acc.y = fmaf(w.x, v0.y, acc.y);
        acc.z = fmaf(w.x, v0.z, acc.z); acc.w = fmaf(w.x, v0.w, acc.w);
        acc.x = fmaf(w.y, v1.x, acc.x); acc.y = fmaf(w.y, v1.y, acc.y);
        acc.z = fmaf(w.y, v1.z, acc.z); acc.w = fmaf(w.y, v1.w, acc.w);
        acc.x = fmaf(w.z, v2.x, acc.x); acc.y = fmaf(w.z, v2.y, acc.y);
        acc.z = fmaf(w.z, v2.z, acc.z); acc.w = fmaf(w.z, v2.w, acc.w);
        acc.x = fmaf(w.w, v3.x, acc.x); acc.y = fmaf(w.w, v3.y, acc.y);
        acc.z = fmaf(w.w, v3.z, acc.z); acc.w = fmaf(w.w, v3.w, acc.w);
    }
    if (bq < M_) *(float4*)&samp[(size_t)bq * 256 + c] = acc;
}

// ---------------------------------------------------------------------------
extern "C" void kernel_launch(void* const* d_in, const int* in_sizes, int n_in,
                              void* d_out, int out_size, void* d_ws, size_t ws_size,
                              hipStream_t stream) {
    const float* query  = (const float*)d_in[0];
    const float* refp   = (const float*)d_in[1];
    const float* value  = (const float*)d_in[2];
    const float* W_off  = (const float*)d_in[3];
    const float* b_off  = (const float*)d_in[4];
    const float* W_attn = (const float*)d_in[5];
    const float* b_attn = (const float*)d_in[6];
    const float* W_val  = (const float*)d_in[7];
    const float* b_val  = (const float*)d_in[8];
    const float* W_out  = (const float*)d_in[9];
    const float* b_out  = (const float*)d_in[10];
    float* out = (float*)d_out;

    const int M = M_;
    float* ws = (float*)d_ws;
    float* ws_v    = ws;                           // M*256 f32
    float* ws_off  = ws_v + (size_t)M * 256;       // M*256 f32
    float* ws_attn = ws_off + (size_t)M * 256;     // M*128 f32
    float* ws_samp = ws_attn + (size_t)M * 128;    // M*256 f32

    // WT buffers overlap dead regions: WT_{val,off,attn} live in ws_samp until
    // the sampler writes it (they're consumed by GEMMs 1-3 first); WT_out goes
    // into ws_v after the sampler has consumed the value projection.
    u16* WT_val  = (u16*)ws_samp;                  // 256*256 bf16
    u16* WT_off  = WT_val + 256 * 256;
    u16* WT_attn = WT_off + 256 * 256;             // 128*256 bf16
    u16* WT_out  = (u16*)ws_v;

    const int gy = (M + 127) / 128;  // 181

    transpose_cast3<<<dim3(8, 8, 3), 256, 0, stream>>>(W_val, W_off, W_attn,
                                                       WT_val, WT_off, WT_attn);
    gemm_bf16<256><<<dim3(2, gy), 256, 0, stream>>>(value, WT_val, b_val, ws_v, M);
    gemm_bf16<256><<<dim3(2, gy), 256, 0, stream>>>(query, WT_off, b_off, ws_off, M);
    gemm_bf16<128><<<dim3(1, gy), 256, 0, stream>>>(query, WT_attn, b_attn, ws_attn, M);
    msda_sample_v2<<<dim3((M + 3) / 4), 256, 0, stream>>>(ws_v, ws_off, ws_attn, refp, ws_samp);
    transpose_cast3<<<dim3(8, 8, 1), 256, 0, stream>>>(W_out, W_out, W_out,
                                                       WT_out, WT_out, WT_out);
    gemm_bf16<256><<<dim3(2, gy), 256, 0, stream>>>(ws_samp, WT_out, b_out, out, M);
}

// Round 3
// 141.030 us; speedup vs baseline: 2.8302x; 1.2367x over previous
//
#include <hip/hip_runtime.h>
#include <cmath>

#define B_    2
#define NQ_   11531
#define NV_   11531
#define M_    (B_ * NQ_)   // 23062

typedef unsigned short u16;
typedef __attribute__((ext_vector_type(8))) short bf16x8;
typedef __attribute__((ext_vector_type(4))) float f32x4;

__device__ __forceinline__ u16 f2bf(float f) {
    union { float f; unsigned u; } v; v.f = f;
    unsigned r = v.u + 0x7FFFu + ((v.u >> 16) & 1u);  // RNE
    return (u16)(r >> 16);
}
__device__ __forceinline__ float bf2f(u16 h) {
    union { unsigned u; float f; } v; v.u = ((unsigned)h) << 16; return v.f;
}

// ---------------------------------------------------------------------------
// Transpose + cast 4 weight matrices: W[K=256][N] fp32 -> WT[N][256] bf16.
// z=0: W_val->WT_val; z=1: W_off->WT_oa[0:256]; z=2: W_attn->WT_oa[256:384];
// z=3: W_out->WT_out. grid (8,8,4), block 256.
// ---------------------------------------------------------------------------
__global__ __launch_bounds__(256) void transpose_cast4(
    const float* __restrict__ Wv, const float* __restrict__ Wo,
    const float* __restrict__ Wa, const float* __restrict__ Wu,
    u16* __restrict__ Tv, u16* __restrict__ Toa, u16* __restrict__ Tu) {
    const int z = blockIdx.z;
    const float* W; u16* T; int N; int rowoff = 0;
    if (z == 0)      { W = Wv; T = Tv;  N = 256; }
    else if (z == 1) { W = Wo; T = Toa; N = 256; }
    else if (z == 2) { W = Wa; T = Toa; N = 128; rowoff = 256; }
    else             { W = Wu; T = Tu;  N = 256; }
    const int n0 = blockIdx.x * 32, k0 = blockIdx.y * 32;
    if (n0 >= N) return;
    __shared__ float t[32][33];
    const int c = threadIdx.x & 31, r0 = threadIdx.x >> 5;
#pragma unroll
    for (int i = 0; i < 4; ++i)
        t[r0 + i * 8][c] = W[(size_t)(k0 + r0 + i * 8) * N + n0 + c];
    __syncthreads();
#pragma unroll
    for (int i = 0; i < 4; ++i)
        T[(size_t)(rowoff + n0 + r0 + i * 8) * 256 + k0 + c] = f2bf(t[c][r0 + i * 8]);
}

// ---------------------------------------------------------------------------
// bf16 MFMA GEMM: C[M x TN] = A[M x 256] * WT^T + bias.
// A fp32 (cast in staging) or bf16 (ABF). Output fp32 or bf16 (OBF).
// WT is [TN][256] bf16. 128x128 tile, 4 waves (2x2), 16x16x32 MFMA.
// For TN=384 the bias is split: cols 0..255 bias, 256..383 bias2.
// ---------------------------------------------------------------------------
template <int TN, bool ABF, bool OBF>
__global__ __launch_bounds__(256) void gemm_bf16(const void* __restrict__ Av,
                                                 const u16* __restrict__ WT,
                                                 const float* __restrict__ bias,
                                                 const float* __restrict__ bias2,
                                                 void* __restrict__ Cv, int M) {
    constexpr int K = 256;
    __shared__ __align__(16) short A_l[128 * 40];
    __shared__ __align__(16) short B_l[128 * 40];
    const int tid = threadIdx.x;
    const int bm = blockIdx.y * 128;
    const int bn = blockIdx.x * 128;
    const int w = tid >> 6;
    const int lane = tid & 63;
    const int wr = (w >> 1) * 64;
    const int wc = (w & 1) * 64;
    const int lr = lane & 15;
    const int kg = (lane >> 4) * 8;

    f32x4 acc[4][4] = {};

    for (int k0 = 0; k0 < K; k0 += 32) {
        if constexpr (!ABF) {
            const float* A = (const float*)Av;
#pragma unroll
            for (int i = 0; i < 4; ++i) {
                const int vid = tid + i * 256;       // float4 id 0..1023
                const int ar = vid >> 3;             // 0..127
                const int ak = (vid & 7) * 4;        // 0..28
                const int gr = bm + ar;
                float4 av = make_float4(0.f, 0.f, 0.f, 0.f);
                if (gr < M) av = *(const float4*)&A[(size_t)gr * K + k0 + ak];
                ushort4 hv;
                hv.x = f2bf(av.x); hv.y = f2bf(av.y); hv.z = f2bf(av.z); hv.w = f2bf(av.w);
                *(ushort4*)&A_l[ar * 40 + ak] = hv;
            }
        } else {
            const u16* A = (const u16*)Av;
#pragma unroll
            for (int i = 0; i < 2; ++i) {
                const int vid = tid + i * 256;       // 8-short chunk 0..511
                const int ar = vid >> 2;             // 0..127
                const int ak = (vid & 3) * 8;        // 0,8,16,24
                const int gr = bm + ar;
                uint4 hv = make_uint4(0u, 0u, 0u, 0u);
                if (gr < M) hv = *(const uint4*)&A[(size_t)gr * K + k0 + ak];
                *(uint4*)&A_l[ar * 40 + ak] = hv;
            }
        }
        // stage B tile (128 n x 32 k) from bf16 WT[n][k]
#pragma unroll
        for (int i = 0; i < 2; ++i) {
            const int vid = tid + i * 256;
            const int nr = vid >> 2;
            const int kk = (vid & 3) * 8;
            const uint4 wv = *(const uint4*)&WT[(size_t)(bn + nr) * K + k0 + kk];
            *(uint4*)&B_l[nr * 40 + kk] = wv;
        }
        __syncthreads();
        bf16x8 af[4], bfr[4];
#pragma unroll
        for (int m = 0; m < 4; ++m)
            af[m] = *(const bf16x8*)&A_l[(wr + m * 16 + lr) * 40 + kg];
#pragma unroll
        for (int n = 0; n < 4; ++n)
            bfr[n] = *(const bf16x8*)&B_l[(wc + n * 16 + lr) * 40 + kg];
#pragma unroll
        for (int m = 0; m < 4; ++m)
#pragma unroll
            for (int n = 0; n < 4; ++n)
                acc[m][n] = __builtin_amdgcn_mfma_f32_16x16x32_bf16(af[m], bfr[n], acc[m][n], 0, 0, 0);
        __syncthreads();
    }

#pragma unroll
    for (int n = 0; n < 4; ++n) {
        const int gcol = bn + wc + n * 16 + lr;
        const float bv = (TN == 384 && gcol >= 256) ? bias2[gcol - 256] : bias[gcol];
#pragma unroll
        for (int m = 0; m < 4; ++m) {
            const int rbase = bm + wr + m * 16 + (lane >> 4) * 4;
#pragma unroll
            for (int j = 0; j < 4; ++j) {
                const int grow = rbase + j;
                if (grow < M) {
                    const float o = acc[m][n][j] + bv;
                    if constexpr (OBF) ((u16*)Cv)[(size_t)grow * TN + gcol] = f2bf(o);
                    else               ((float*)Cv)[(size_t)grow * TN + gcol] = o;
                }
            }
        }
    }
}

// ---------------------------------------------------------------------------
// Sampler v3: block = 256 threads handles 4 queries. v is bf16.
// Phase 1: 512 sample-points computed once (softmax + bilinear*attn weights +
//          clamped row indices) -> LDS.
// Phase 2: 64 lanes/query, 4 channels/lane, bf16 gathers with explicit
//          next-iteration software pipeline (keeps 8 loads in flight).
// ---------------------------------------------------------------------------
__global__ __launch_bounds__(256) void msda_sample_v3(
    const u16* __restrict__ v,       // (B*NV, 256) bf16 projected value
    const float* __restrict__ oa,    // (B*NQ, 384): 256 offsets + 128 logits
    const float* __restrict__ refp,  // (B, NQ, 4, 2)
    u16* __restrict__ samp) {        // (B*NQ, 256) bf16
    __shared__ __align__(16) float4 s_w4[512];  // [(qi*16+sp)*8 + h]
    __shared__ __align__(16) int4   s_i4[512];
    const int tid = threadIdx.x;
    const int bq0 = blockIdx.x * 4;

#pragma unroll
    for (int half = 0; half < 2; ++half) {
        const int s = tid + half * 256;
        const int qi = s >> 7;
        const int rem = s & 127;          // h*16 + l*4 + p
        const int sampi = rem & 15;
        const int l = sampi >> 2;
        const int h = rem >> 4;
        int bq = bq0 + qi;
        if (bq >= M_) bq = M_ - 1;        // clamped lane: valid reads, unused result
        const int b = bq / NQ_;

        const float logit = oa[(size_t)bq * 384 + 256 + rem];
        float mx = logit;
#pragma unroll
        for (int t = 8; t >= 1; t >>= 1) mx = fmaxf(mx, __shfl_xor(mx, t, 16));
        const float e = __expf(logit - mx);
        float sm = e;
#pragma unroll
        for (int t = 8; t >= 1; t >>= 1) sm += __shfl_xor(sm, t, 16);
        const float aw = e / sm;

        const float2 off = *(const float2*)&oa[(size_t)bq * 384 + rem * 2];
        const float2 rxy = *(const float2*)&refp[(size_t)bq * 8 + l * 2];
        const int lw = (l == 0) ? 114 : (l == 1) ? 57 : (l == 2) ? 29 : 15;
        const int lh = (l == 0) ? 76 : (l == 1) ? 38 : (l == 2) ? 19 : 10;
        const int st = (l == 0) ? 0 : (l == 1) ? 8664 : (l == 2) ? 10830 : 11381;
        const int base = b * NV_ + st;

        const float px = rxy.x * (float)lw + off.x - 0.5f;
        const float py = rxy.y * (float)lh + off.y - 0.5f;
        const float x0f = floorf(px), y0f = floorf(py);
        const int x0 = (int)x0f, y0 = (int)y0f;
        const float fx = px - x0f, fy = py - y0f;
        const bool vx0 = (x0 >= 0) && (x0 < lw);
        const bool vx1 = (x0 >= -1) && (x0 < lw - 1);
        const bool vy0 = (y0 >= 0) && (y0 < lh);
        const bool vy1 = (y0 >= -1) && (y0 < lh - 1);
        const int r0 = base + y0 * lw + x0;
        const int r1 = r0 + lw;
        float4 wv; int4 iv;
        wv.x = (vy0 && vx0) ? aw * (1.f - fx) * (1.f - fy) : 0.f; iv.x = (vy0 && vx0) ? r0 : 0;
        wv.y = (vy0 && vx1) ? aw * fx * (1.f - fy) : 0.f;         iv.y = (vy0 && vx1) ? r0 + 1 : 0;
        wv.z = (vy1 && vx0) ? aw * (1.f - fx) * fy : 0.f;         iv.z = (vy1 && vx0) ? r1 : 0;
        wv.w = (vy1 && vx1) ? aw * fx * fy : 0.f;                 iv.w = (vy1 && vx1) ? r1 + 1 : 0;
        const int slot = (qi * 16 + sampi) * 8 + h;
        s_w4[slot] = wv;
        s_i4[slot] = iv;
    }
    __syncthreads();

    const int qi = tid >> 6;
    const int lane = tid & 63;
    const int h = lane >> 3;
    const int c = lane * 4;               // channel = h*32 + (lane&7)*4
    const int bq = bq0 + qi;
    const int slotbase = qi * 128 + h;    // + sp*8

    float acc0 = 0.f, acc1 = 0.f, acc2 = 0.f, acc3 = 0.f;
    float4 wc = s_w4[slotbase];
    int4 ic = s_i4[slotbase];
    ushort4 a0 = *(const ushort4*)&v[((size_t)ic.x << 8) + c];
    ushort4 a1 = *(const ushort4*)&v[((size_t)ic.y << 8) + c];
    ushort4 a2 = *(const ushort4*)&v[((size_t)ic.z << 8) + c];
    ushort4 a3 = *(const ushort4*)&v[((size_t)ic.w << 8) + c];

#pragma unroll
    for (int sp = 0; sp < 16; ++sp) {
        float4 wn;
        ushort4 b0, b1, b2, b3;
        if (sp < 15) {                      // prefetch next point's 4 corners
            wn = s_w4[slotbase + (sp + 1) * 8];
            const int4 in_ = s_i4[slotbase + (sp + 1) * 8];
            b0 = *(const ushort4*)&v[((size_t)in_.x << 8) + c];
            b1 = *(const ushort4*)&v[((size_t)in_.y << 8) + c];
            b2 = *(const ushort4*)&v[((size_t)in_.z << 8) + c];
            b3 = *(const ushort4*)&v[((size_t)in_.w << 8) + c];
        }
        acc0 = fmaf(wc.x, bf2f(a0.x), acc0); acc1 = fmaf(wc.x, bf2f(a0.y), acc1);
        acc2 = fmaf(wc.x, bf2f(a0.z), acc2); acc3 = fmaf(wc.x, bf2f(a0.w), acc3);
        acc0 = fmaf(wc.y, bf2f(a1.x), acc0); acc1 = fmaf(wc.y, bf2f(a1.y), acc1);
        acc2 = fmaf(wc.y, bf2f(a1.z), acc2); acc3 = fmaf(wc.y, bf2f(a1.w), acc3);
        acc0 = fmaf(wc.z, bf2f(a2.x), acc0); acc1 = fmaf(wc.z, bf2f(a2.y), acc1);
        acc2 = fmaf(wc.z, bf2f(a2.z), acc2); acc3 = fmaf(wc.z, bf2f(a2.w), acc3);
        acc0 = fmaf(wc.w, bf2f(a3.x), acc0); acc1 = fmaf(wc.w, bf2f(a3.y), acc1);
        acc2 = fmaf(wc.w, bf2f(a3.z), acc2); acc3 = fmaf(wc.w, bf2f(a3.w), acc3);
        if (sp < 15) { wc = wn; a0 = b0; a1 = b1; a2 = b2; a3 = b3; }
    }
    if (bq < M_) {
        ushort4 o;
        o.x = f2bf(acc0); o.y = f2bf(acc1); o.z = f2bf(acc2); o.w = f2bf(acc3);
        *(ushort4*)&samp[(size_t)bq * 256 + c] = o;
    }
}

// ---------------------------------------------------------------------------
extern "C" void kernel_launch(void* const* d_in, const int* in_sizes, int n_in,
                              void* d_out, int out_size, void* d_ws, size_t ws_size,
                              hipStream_t stream) {
    const float* query  = (const float*)d_in[0];
    const float* refp   = (const float*)d_in[1];
    const float* value  = (const float*)d_in[2];
    const float* W_off  = (const float*)d_in[3];
    const float* b_off  = (const float*)d_in[4];
    const float* W_attn = (const float*)d_in[5];
    const float* b_attn = (const float*)d_in[6];
    const float* W_val  = (const float*)d_in[7];
    const float* b_val  = (const float*)d_in[8];
    const float* W_out  = (const float*)d_in[9];
    const float* b_out  = (const float*)d_in[10];
    float* out = (float*)d_out;

    const int M = M_;
    u16*   ws_v    = (u16*)d_ws;                          // M*256 bf16
    float* ws_oa   = (float*)(ws_v + (size_t)M * 256);    // M*384 f32
    u16*   ws_samp = (u16*)(ws_oa + (size_t)M * 384);     // M*256 bf16
    u16*   WT_val  = ws_samp + (size_t)M * 256;           // 256*256 bf16
    u16*   WT_oa   = WT_val + 256 * 256;                  // 384*256 bf16
    u16*   WT_out  = WT_oa + 384 * 256;                   // 256*256 bf16

    const int gy = (M + 127) / 128;  // 181

    transpose_cast4<<<dim3(8, 8, 4), 256, 0, stream>>>(W_val, W_off, W_attn, W_out,
                                                       WT_val, WT_oa, WT_out);
    gemm_bf16<256, false, true><<<dim3(2, gy), 256, 0, stream>>>(value, WT_val, b_val, b_val, ws_v, M);
    gemm_bf16<384, false, false><<<dim3(3, gy), 256, 0, stream>>>(query, WT_oa, b_off, b_attn, ws_oa, M);
    msda_sample_v3<<<dim3((M + 3) / 4), 256, 0, stream>>>(ws_v, ws_oa, refp, ws_samp);
    gemm_bf16<256, true, false><<<dim3(2, gy), 256, 0, stream>>>(ws_samp, WT_out, b_out, b_out, out, M);
}

// Round 4
// 131.938 us; speedup vs baseline: 3.0252x; 1.0689x over previous
//
#include <hip/hip_runtime.h>
#include <cmath>

#define B_    2
#define NQ_   11531
#define NV_   11531
#define M_    (B_ * NQ_)   // 23062

typedef unsigned short u16;
typedef __attribute__((ext_vector_type(8))) short bf16x8;
typedef __attribute__((ext_vector_type(4))) float f32x4;

__device__ __forceinline__ u16 f2bf(float f) {
    union { float f; unsigned u; } v; v.f = f;
    unsigned r = v.u + 0x7FFFu + ((v.u >> 16) & 1u);  // RNE
    return (u16)(r >> 16);
}
__device__ __forceinline__ float bf2f(u16 h) {
    union { unsigned u; float f; } v; v.u = ((unsigned)h) << 16; return v.f;
}

// ---------------------------------------------------------------------------
// Transpose + cast 4 weight matrices: W[K=256][N] fp32 -> WT[N][256] bf16.
// ---------------------------------------------------------------------------
__global__ __launch_bounds__(256) void transpose_cast4(
    const float* __restrict__ Wv, const float* __restrict__ Wo,
    const float* __restrict__ Wa, const float* __restrict__ Wu,
    u16* __restrict__ Tv, u16* __restrict__ Toa, u16* __restrict__ Tu) {
    const int z = blockIdx.z;
    const float* W; u16* T; int N; int rowoff = 0;
    if (z == 0)      { W = Wv; T = Tv;  N = 256; }
    else if (z == 1) { W = Wo; T = Toa; N = 256; }
    else if (z == 2) { W = Wa; T = Toa; N = 128; rowoff = 256; }
    else             { W = Wu; T = Tu;  N = 256; }
    const int n0 = blockIdx.x * 32, k0 = blockIdx.y * 32;
    if (n0 >= N) return;
    __shared__ float t[32][33];
    const int c = threadIdx.x & 31, r0 = threadIdx.x >> 5;
#pragma unroll
    for (int i = 0; i < 4; ++i)
        t[r0 + i * 8][c] = W[(size_t)(k0 + r0 + i * 8) * N + n0 + c];
    __syncthreads();
#pragma unroll
    for (int i = 0; i < 4; ++i)
        T[(size_t)(rowoff + n0 + r0 + i * 8) * 256 + k0 + c] = f2bf(t[c][r0 + i * 8]);
}

// ---------------------------------------------------------------------------
// bf16 MFMA GEMM body: C[bm:bm+128, bn:bn+128] for C = A[M x 256] * WT^T + b.
// K_STEP=64 (2 MFMA K-subtiles per stage, 2 barriers per 64-K). LDS stride 72
// shorts (144 B): 16B-aligned, 2-way max bank aliasing on b128 reads (free).
// ---------------------------------------------------------------------------
template <int TN, bool ABF, bool OBF>
__device__ __forceinline__ void gemm_body(const void* __restrict__ Av,
                                          const u16* __restrict__ WT,
                                          const float* __restrict__ bias,
                                          const float* __restrict__ bias2,
                                          void* __restrict__ Cv, int M,
                                          int bm, int bn,
                                          short* A_l, short* B_l) {
    constexpr int K = 256;
    const int tid = threadIdx.x;
    const int w = tid >> 6;
    const int lane = tid & 63;
    const int wr = (w >> 1) * 64;
    const int wc = (w & 1) * 64;
    const int lr = lane & 15;

    f32x4 acc[4][4] = {};

    for (int k0 = 0; k0 < K; k0 += 64) {
        if constexpr (!ABF) {
            const float* A = (const float*)Av;
#pragma unroll
            for (int i = 0; i < 8; ++i) {
                const int vid = tid + i * 256;       // float4 id 0..2047
                const int ar = vid >> 4;             // 0..127
                const int ak = (vid & 15) * 4;       // 0..60
                const int gr = bm + ar;
                float4 av = make_float4(0.f, 0.f, 0.f, 0.f);
                if (gr < M) av = *(const float4*)&A[(size_t)gr * K + k0 + ak];
                ushort4 hv;
                hv.x = f2bf(av.x); hv.y = f2bf(av.y); hv.z = f2bf(av.z); hv.w = f2bf(av.w);
                *(ushort4*)&A_l[ar * 72 + ak] = hv;
            }
        } else {
            const u16* A = (const u16*)Av;
#pragma unroll
            for (int i = 0; i < 4; ++i) {
                const int vid = tid + i * 256;       // 8-short chunk 0..1023
                const int ar = vid >> 3;             // 0..127
                const int ak = (vid & 7) * 8;        // 0..56
                const int gr = bm + ar;
                uint4 hv = make_uint4(0u, 0u, 0u, 0u);
                if (gr < M) hv = *(const uint4*)&A[(size_t)gr * K + k0 + ak];
                *(uint4*)&A_l[ar * 72 + ak] = hv;
            }
        }
#pragma unroll
        for (int i = 0; i < 4; ++i) {
            const int vid = tid + i * 256;           // 8-short chunk 0..1023
            const int nr = vid >> 3;                 // 0..127
            const int kk = (vid & 7) * 8;            // 0..56
            const uint4 wv = *(const uint4*)&WT[(size_t)(bn + nr) * K + k0 + kk];
            *(uint4*)&B_l[nr * 72 + kk] = wv;
        }
        __syncthreads();
#pragma unroll
        for (int half = 0; half < 2; ++half) {
            const int kg = half * 32 + (lane >> 4) * 8;
            bf16x8 af[4], bfr[4];
#pragma unroll
            for (int m = 0; m < 4; ++m)
                af[m] = *(const bf16x8*)&A_l[(wr + m * 16 + lr) * 72 + kg];
#pragma unroll
            for (int n = 0; n < 4; ++n)
                bfr[n] = *(const bf16x8*)&B_l[(wc + n * 16 + lr) * 72 + kg];
#pragma unroll
            for (int m = 0; m < 4; ++m)
#pragma unroll
                for (int n = 0; n < 4; ++n)
                    acc[m][n] = __builtin_amdgcn_mfma_f32_16x16x32_bf16(af[m], bfr[n], acc[m][n], 0, 0, 0);
        }
        __syncthreads();
    }

#pragma unroll
    for (int n = 0; n < 4; ++n) {
        const int gcol = bn + wc + n * 16 + lr;
        const float bv = (TN == 384 && gcol >= 256) ? bias2[gcol - 256] : bias[gcol];
#pragma unroll
        for (int m = 0; m < 4; ++m) {
            const int rbase = bm + wr + m * 16 + (lane >> 4) * 4;
#pragma unroll
            for (int j = 0; j < 4; ++j) {
                const int grow = rbase + j;
                if (grow < M) {
                    const float o = acc[m][n][j] + bv;
                    if constexpr (OBF) ((u16*)Cv)[(size_t)grow * TN + gcol] = f2bf(o);
                    else               ((float*)Cv)[(size_t)grow * TN + gcol] = o;
                }
            }
        }
    }
}

// Fused stage-1: blocks [0, 2*gy) do value-projection (bf16 out);
// blocks [2*gy, 5*gy) do query->off/attn projection (fp32 out, TN=384).
__global__ __launch_bounds__(256, 4) void gemm_stage1(
    const float* __restrict__ query, const float* __restrict__ value,
    const u16* __restrict__ WT_val, const u16* __restrict__ WT_oa,
    const float* __restrict__ b_val, const float* __restrict__ b_off,
    const float* __restrict__ b_attn,
    u16* __restrict__ ws_v, float* __restrict__ ws_oa, int M, int gy) {
    __shared__ __align__(16) short A_l[128 * 72];
    __shared__ __align__(16) short B_l[128 * 72];
    int blk = blockIdx.x;
    if (blk < 2 * gy) {
        gemm_body<256, false, true>(value, WT_val, b_val, b_val, ws_v, M,
                                    (blk >> 1) * 128, (blk & 1) * 128, A_l, B_l);
    } else {
        blk -= 2 * gy;
        gemm_body<384, false, false>(query, WT_oa, b_off, b_attn, ws_oa, M,
                                     (blk / 3) * 128, (blk % 3) * 128, A_l, B_l);
    }
}

__global__ __launch_bounds__(256, 4) void gemm_out(
    const u16* __restrict__ samp, const u16* __restrict__ WT_out,
    const float* __restrict__ b_out, float* __restrict__ out, int M) {
    __shared__ __align__(16) short A_l[128 * 72];
    __shared__ __align__(16) short B_l[128 * 72];
    const int blk = blockIdx.x;
    gemm_body<256, true, false>(samp, WT_out, b_out, b_out, out, M,
                                (blk >> 1) * 128, (blk & 1) * 128, A_l, B_l);
}

// ---------------------------------------------------------------------------
// Sampler v4: block = 256 threads handles 4 queries. v is bf16.
// Phase 1: 512 sample-points computed once; stores attn*bilinear weights +
//          per-corner BYTE offsets (incl. head base) -> LDS, layout
//          [(qi*8+h)*17 + sampi] (pad 17: conflict-free writes AND reads).
// Phase 2: 64 lanes/query (8 lanes/head, 4 ch/lane), 1-deep prefetch,
//          SGPR-base + 32-bit-offset gathers.
// ---------------------------------------------------------------------------
__global__ __launch_bounds__(256) void msda_sample_v4(
    const u16* __restrict__ v,       // (B*NV, 256) bf16 projected value
    const float* __restrict__ oa,    // (B*NQ, 384): 256 offsets + 128 logits
    const float* __restrict__ refp,  // (B, NQ, 4, 2)
    u16* __restrict__ samp) {        // (B*NQ, 256) bf16
    __shared__ __align__(16) float4 s_w4[543];
    __shared__ __align__(16) int4   s_i4[543];
    const int tid = threadIdx.x;
    const int bq0 = blockIdx.x * 4;

#pragma unroll
    for (int half = 0; half < 2; ++half) {
        const int s = tid + half * 256;
        const int qi = s >> 7;
        const int rem = s & 127;          // h*16 + l*4 + p
        const int sampi = rem & 15;
        const int l = sampi >> 2;
        const int h = rem >> 4;
        int bq = bq0 + qi;
        if (bq >= M_) bq = M_ - 1;        // clamped lane: valid reads, unused result
        const int b = bq / NQ_;

        const float logit = oa[(size_t)bq * 384 + 256 + rem];
        float mx = logit;
#pragma unroll
        for (int t = 8; t >= 1; t >>= 1) mx = fmaxf(mx, __shfl_xor(mx, t, 16));
        const float e = __expf(logit - mx);
        float sm = e;
#pragma unroll
        for (int t = 8; t >= 1; t >>= 1) sm += __shfl_xor(sm, t, 16);
        const float aw = e / sm;

        const float2 off = *(const float2*)&oa[(size_t)bq * 384 + rem * 2];
        const float2 rxy = *(const float2*)&refp[(size_t)bq * 8 + l * 2];
        const int lw = (l == 0) ? 114 : (l == 1) ? 57 : (l == 2) ? 29 : 15;
        const int lh = (l == 0) ? 76 : (l == 1) ? 38 : (l == 2) ? 19 : 10;
        const int st = (l == 0) ? 0 : (l == 1) ? 8664 : (l == 2) ? 10830 : 11381;
        const int base = b * NV_ + st;

        const float px = rxy.x * (float)lw + off.x - 0.5f;
        const float py = rxy.y * (float)lh + off.y - 0.5f;
        const float x0f = floorf(px), y0f = floorf(py);
        const int x0 = (int)x0f, y0 = (int)y0f;
        const float fx = px - x0f, fy = py - y0f;
        const bool vx0 = (x0 >= 0) && (x0 < lw);
        const bool vx1 = (x0 >= -1) && (x0 < lw - 1);
        const bool vy0 = (y0 >= 0) && (y0 < lh);
        const bool vy1 = (y0 >= -1) && (y0 < lh - 1);
        const int h64 = h * 64;                       // head base, bytes
        const int r0 = (base + y0 * lw + x0) * 512 + h64;   // byte offsets
        const int r1 = r0 + lw * 512;
        float4 wv; int4 iv;
        wv.x = (vy0 && vx0) ? aw * (1.f - fx) * (1.f - fy) : 0.f; iv.x = (vy0 && vx0) ? r0 : 0;
        wv.y = (vy0 && vx1) ? aw * fx * (1.f - fy) : 0.f;         iv.y = (vy0 && vx1) ? r0 + 512 : 0;
        wv.z = (vy1 && vx0) ? aw * (1.f - fx) * fy : 0.f;         iv.z = (vy1 && vx0) ? r1 : 0;
        wv.w = (vy1 && vx1) ? aw * fx * fy : 0.f;                 iv.w = (vy1 && vx1) ? r1 + 512 : 0;
        const int slot = (qi * 8 + h) * 17 + sampi;   // contiguous per 16-lane run
        s_w4[slot] = wv;
        s_i4[slot] = iv;
    }
    __syncthreads();

    const int qi = tid >> 6;
    const int lane = tid & 63;
    const int h = lane >> 3;
    const int coff = (lane & 7) * 8;      // byte offset within head (4 ch * 2B)
    const int bq = bq0 + qi;
    const int slotbase = (qi * 8 + h) * 17;
    const char* vb = (const char*)v;

    float acc0 = 0.f, acc1 = 0.f, acc2 = 0.f, acc3 = 0.f;
    float4 wc = s_w4[slotbase];
    int4 ic = s_i4[slotbase];
    ushort4 a0 = *(const ushort4*)(vb + (unsigned)(ic.x + coff));
    ushort4 a1 = *(const ushort4*)(vb + (unsigned)(ic.y + coff));
    ushort4 a2 = *(const ushort4*)(vb + (unsigned)(ic.z + coff));
    ushort4 a3 = *(const ushort4*)(vb + (unsigned)(ic.w + coff));

#pragma unroll
    for (int sp = 0; sp < 16; ++sp) {
        float4 wn;
        ushort4 b0, b1, b2, b3;
        if (sp < 15) {                      // prefetch next point's 4 corners
            wn = s_w4[slotbase + sp + 1];
            const int4 in_ = s_i4[slotbase + sp + 1];
            b0 = *(const ushort4*)(vb + (unsigned)(in_.x + coff));
            b1 = *(const ushort4*)(vb + (unsigned)(in_.y + coff));
            b2 = *(const ushort4*)(vb + (unsigned)(in_.z + coff));
            b3 = *(const ushort4*)(vb + (unsigned)(in_.w + coff));
        }
        acc0 = fmaf(wc.x, bf2f(a0.x), acc0); acc1 = fmaf(wc.x, bf2f(a0.y), acc1);
        acc2 = fmaf(wc.x, bf2f(a0.z), acc2); acc3 = fmaf(wc.x, bf2f(a0.w), acc3);
        acc0 = fmaf(wc.y, bf2f(a1.x), acc0); acc1 = fmaf(wc.y, bf2f(a1.y), acc1);
        acc2 = fmaf(wc.y, bf2f(a1.z), acc2); acc3 = fmaf(wc.y, bf2f(a1.w), acc3);
        acc0 = fmaf(wc.z, bf2f(a2.x), acc0); acc1 = fmaf(wc.z, bf2f(a2.y), acc1);
        acc2 = fmaf(wc.z, bf2f(a2.z), acc2); acc3 = fmaf(wc.z, bf2f(a2.w), acc3);
        acc0 = fmaf(wc.w, bf2f(a3.x), acc0); acc1 = fmaf(wc.w, bf2f(a3.y), acc1);
        acc2 = fmaf(wc.w, bf2f(a3.z), acc2); acc3 = fmaf(wc.w, bf2f(a3.w), acc3);
        if (sp < 15) { wc = wn; a0 = b0; a1 = b1; a2 = b2; a3 = b3; }
    }
    if (bq < M_) {
        ushort4 o;
        o.x = f2bf(acc0); o.y = f2bf(acc1); o.z = f2bf(acc2); o.w = f2bf(acc3);
        *(ushort4*)&samp[(size_t)bq * 256 + (h * 32 + (lane & 7) * 4)] = o;
    }
}

// ---------------------------------------------------------------------------
extern "C" void kernel_launch(void* const* d_in, const int* in_sizes, int n_in,
                              void* d_out, int out_size, void* d_ws, size_t ws_size,
                              hipStream_t stream) {
    const float* query  = (const float*)d_in[0];
    const float* refp   = (const float*)d_in[1];
    const float* value  = (const float*)d_in[2];
    const float* W_off  = (const float*)d_in[3];
    const float* b_off  = (const float*)d_in[4];
    const float* W_attn = (const float*)d_in[5];
    const float* b_attn = (const float*)d_in[6];
    const float* W_val  = (const float*)d_in[7];
    const float* b_val  = (const float*)d_in[8];
    const float* W_out  = (const float*)d_in[9];
    const float* b_out  = (const float*)d_in[10];
    float* out = (float*)d_out;

    const int M = M_;
    u16*   ws_v    = (u16*)d_ws;                          // M*256 bf16
    float* ws_oa   = (float*)(ws_v + (size_t)M * 256);    // M*384 f32
    u16*   ws_samp = (u16*)(ws_oa + (size_t)M * 384);     // M*256 bf16
    u16*   WT_val  = ws_samp + (size_t)M * 256;           // 256*256 bf16
    u16*   WT_oa   = WT_val + 256 * 256;                  // 384*256 bf16
    u16*   WT_out  = WT_oa + 384 * 256;                   // 256*256 bf16

    const int gy = (M + 127) / 128;  // 181

    transpose_cast4<<<dim3(8, 8, 4), 256, 0, stream>>>(W_val, W_off, W_attn, W_out,
                                                       WT_val, WT_oa, WT_out);
    gemm_stage1<<<dim3(5 * gy), 256, 0, stream>>>(query, value, WT_val, WT_oa,
                                                  b_val, b_off, b_attn,
                                                  ws_v, ws_oa, M, gy);
    msda_sample_v4<<<dim3((M + 3) / 4), 256, 0, stream>>>(ws_v, ws_oa, refp, ws_samp);
    gemm_out<<<dim3(2 * gy), 256, 0, stream>>>(ws_samp, WT_out, b_out, out, M);
}